// Round 12
// baseline (413.301 us; speedup 1.0000x reference)
//
#include <hip/hip_runtime.h>
#include <math.h>
#include <float.h>

#define L_   4096
#define M_   8192
#define H_   8
#define D_   64
#define KK   45          // 5 * ceil(ln(4096))

// ws layout in float2 units
#define WS_C   0         // c[4096]  : e^{-i pi j^2 / 8191}
#define WS_D   4096      // d[4096]  : e^{+i pi j^2 / 8190}
#define WS_TW  8192      // tw[8192] : e^{-2 pi i j / 8192} (fp64-accurate; setup_filters only)
#define WS_H1  16384     // H1s[8192]: radix8-DIF(conj-chirp c), pre-scaled 1/8192, digit-reversed
#define WS_H2  24576     // H2s[8192]: same for d
#define WS_QKV 32768     // float2 offset where staged q/k/v planes start
// tables: 256 KB; then q/k/v planes: 3 x 1M floats = 12 MB

__device__ __forceinline__ float2 cadd(float2 a, float2 b) { return make_float2(a.x + b.x, a.y + b.y); }
__device__ __forceinline__ float2 csub(float2 a, float2 b) { return make_float2(a.x - b.x, a.y - b.y); }
__device__ __forceinline__ float2 cmulf(float2 a, float2 b) {
  return make_float2(a.x * b.x - a.y * b.y, a.x * b.y + a.y * b.x);
}
__device__ __forceinline__ float2 cmulcf(float2 a, float2 b) {  // a * conj(b)
  return make_float2(a.x * b.x + a.y * b.y, a.y * b.x - a.x * b.y);
}

// register twiddle: e^{-2 pi i e / 8192}
__device__ __forceinline__ float2 twf(int e) {
  float s, c;
  __sincosf((float)e * -7.66990394e-4f, &s, &c);   // -2*pi/8192
  return make_float2(c, s);
}

// w[k] = W^(k*e), W = e^{-2pi i/8192}; chained products (<=3 deep)
__device__ __forceinline__ void mk_tw(int e, float2 w[8]) {
  w[1] = twf(e);
  w[2] = cmulf(w[1], w[1]);
  w[3] = cmulf(w[2], w[1]);
  w[4] = cmulf(w[2], w[2]);
  w[5] = cmulf(w[4], w[1]);
  w[6] = cmulf(w[3], w[3]);
  w[7] = cmulf(w[4], w[3]);
}

// ---------------- radix-8 butterfly cores (no twiddle mult inside) ----------------
// forward: x <- DFT8(x);  W8 = e^{-i pi/4} = (1-i)/sqrt2
__device__ __forceinline__ void bfly8_dif(float2 x[8]) {
  const float2 a0 = cadd(x[0], x[4]), a1 = csub(x[0], x[4]);
  const float2 a2 = cadd(x[2], x[6]), a3 = csub(x[2], x[6]);
  const float2 a4 = cadd(x[1], x[5]), a5 = csub(x[1], x[5]);
  const float2 a6 = cadd(x[3], x[7]), a7 = csub(x[3], x[7]);
  const float2 b0 = cadd(a0, a2), b1 = csub(a0, a2);
  const float2 b2 = cadd(a4, a6), b3 = csub(a4, a6);
  const float s = 0.70710678118654752f;
  const float2 c0 = make_float2(a1.x + a3.y, a1.y - a3.x);   // a1 - i a3
  const float2 c1 = make_float2(a1.x - a3.y, a1.y + a3.x);   // a1 + i a3
  const float2 c2 = make_float2(a5.x + a7.y, a5.y - a7.x);   // a5 - i a7
  const float2 c3 = make_float2(a5.x - a7.y, a5.y + a7.x);   // a5 + i a7
  const float2 t2 = make_float2(s * (c2.x + c2.y), s * (c2.y - c2.x));    // W8   * c2
  const float2 t3 = make_float2(s * (c3.y - c3.x), -s * (c3.x + c3.y));   // W8^3 * c3
  x[0] = cadd(b0, b2);
  x[4] = csub(b0, b2);
  x[2] = make_float2(b1.x + b3.y, b1.y - b3.x);              // b1 - i b3
  x[6] = make_float2(b1.x - b3.y, b1.y + b3.x);              // b1 + i b3
  x[1] = cadd(c0, t2);
  x[5] = csub(c0, t2);
  x[3] = cadd(c1, t3);
  x[7] = csub(c1, t3);
}

// inverse (unscaled IDFT8): x_n = sum_k z_k e^{+2pi i nk/8}; W8* = (1+i)/sqrt2
__device__ __forceinline__ void bfly8_dit(float2 x[8]) {
  const float2 a0 = cadd(x[0], x[4]), a1 = csub(x[0], x[4]);
  const float2 a2 = cadd(x[2], x[6]), a3 = csub(x[2], x[6]);
  const float2 a4 = cadd(x[1], x[5]), a5 = csub(x[1], x[5]);
  const float2 a6 = cadd(x[3], x[7]), a7 = csub(x[3], x[7]);
  const float2 b0 = cadd(a0, a2), b1 = csub(a0, a2);
  const float2 b2 = cadd(a4, a6), b3 = csub(a4, a6);
  const float s = 0.70710678118654752f;
  const float2 c0 = make_float2(a1.x - a3.y, a1.y + a3.x);   // a1 + i a3
  const float2 c1 = make_float2(a1.x + a3.y, a1.y - a3.x);   // a1 - i a3
  const float2 c2 = make_float2(a5.x - a7.y, a5.y + a7.x);   // a5 + i a7
  const float2 c3 = make_float2(a5.x + a7.y, a5.y - a7.x);   // a5 - i a7
  const float2 t2 = make_float2(s * (c2.x - c2.y), s * (c2.x + c2.y));    // W8*   * c2
  const float2 t3 = make_float2(-s * (c3.x + c3.y), s * (c3.x - c3.y));   // W8*^3 * c3
  x[0] = cadd(b0, b2);
  x[4] = csub(b0, b2);
  x[2] = make_float2(b1.x - b3.y, b1.y + b3.x);              // b1 + i b3
  x[6] = make_float2(b1.x + b3.y, b1.y - b3.x);              // b1 - i b3
  x[1] = cadd(c0, t2);
  x[5] = csub(c0, t2);
  x[3] = cadd(c1, t3);
  x[7] = csub(c1, t3);
}

// e^{-i pi k/8} constants for the q=2 stage (j=1 butterfly)
#define C8f 0.923879532511287f
#define S8f 0.382683432365090f
#define Q8f 0.707106781186548f

// ---------------- megamid: fwd q=2 r8 + span-1 r2 + H + inv r2 + inv q=2 r8, in registers
// worker wk (0..511) owns float2 slots [wk*16, wk*16+16) of buffer T.
__device__ __forceinline__ void megamid(float2* T, const float2* __restrict__ Hf, int wk) {
  float4* T4 = reinterpret_cast<float4*>(T);
  const float4* H4 = reinterpret_cast<const float4*>(Hf);
  const int b4 = wk << 3;
  const int st = wk & 7;
  float2 ev[8], od[8];
  #pragma unroll
  for (int mm = 0; mm < 8; ++mm) {          // bank-staggered b128 loads
    const int m = (mm + st) & 7;
    const float4 t = T4[b4 + m];
    ev[m] = make_float2(t.x, t.y);
    od[m] = make_float2(t.z, t.w);
  }
  // forward q=2 radix-8 (j=0: twiddles 1; j=1: w_k = e^{-i pi k/8})
  bfly8_dif(ev);
  bfly8_dif(od);
  od[1] = cmulf(od[1], make_float2(C8f, -S8f));
  od[2] = cmulf(od[2], make_float2(Q8f, -Q8f));
  od[3] = cmulf(od[3], make_float2(S8f, -C8f));
  od[4] = make_float2(od[4].y, -od[4].x);                    // * (0,-1)
  od[5] = cmulf(od[5], make_float2(-S8f, -C8f));
  od[6] = cmulf(od[6], make_float2(-Q8f, -Q8f));
  od[7] = cmulf(od[7], make_float2(-C8f, -S8f));
  // span-1 r2 + H pointwise + inverse span-1 r2, per pair m
  #pragma unroll
  for (int m = 0; m < 8; ++m) {
    const float4 h = H4[b4 + m];
    float2 u = cadd(ev[m], od[m]);
    float2 v = csub(ev[m], od[m]);
    u = cmulf(u, make_float2(h.x, h.y));
    v = cmulf(v, make_float2(h.z, h.w));
    ev[m] = cadd(u, v);
    od[m] = csub(u, v);
  }
  // inverse q=2 radix-8: de-twiddle odds (conj), then inverse butterflies
  od[1] = cmulcf(od[1], make_float2(C8f, -S8f));
  od[2] = cmulcf(od[2], make_float2(Q8f, -Q8f));
  od[3] = cmulcf(od[3], make_float2(S8f, -C8f));
  od[4] = make_float2(-od[4].y, od[4].x);                    // * (0,+1)
  od[5] = cmulcf(od[5], make_float2(-S8f, -C8f));
  od[6] = cmulcf(od[6], make_float2(-Q8f, -Q8f));
  od[7] = cmulcf(od[7], make_float2(-C8f, -S8f));
  bfly8_dit(ev);
  bfly8_dit(od);
  #pragma unroll
  for (int mm = 0; mm < 8; ++mm) {
    const int m = (mm + st) & 7;
    T4[b4 + m] = make_float4(ev[m].x, ev[m].y, od[m].x, od[m].y);
  }
}

// generic middle forward stage s (s=1,2), 1024 threads, one butterfly each
__device__ __forceinline__ void r8_fwd_stage(float2* T, int s, int tid) {
  const int q  = 1024 >> (3 * s);
  const int j  = tid & (q - 1);
  const int i0 = ((tid >> (10 - 3 * s)) << (13 - 3 * s)) + j;
  float2 w[8]; mk_tw(j << (3 * s), w);
  float2 x[8];
  #pragma unroll
  for (int k = 0; k < 8; ++k) x[k] = T[i0 + k * q];
  bfly8_dif(x);
  T[i0] = x[0];
  #pragma unroll
  for (int k = 1; k < 8; ++k) T[i0 + k * q] = cmulf(x[k], w[k]);
}

__device__ __forceinline__ void r8_inv_stage(float2* T, int s, int tid) {
  const int q  = 1024 >> (3 * s);
  const int j  = tid & (q - 1);
  const int i0 = ((tid >> (10 - 3 * s)) << (13 - 3 * s)) + j;
  float2 w[8]; mk_tw(j << (3 * s), w);
  float2 x[8];
  #pragma unroll
  for (int k = 0; k < 8; ++k) x[k] = T[i0 + k * q];
  #pragma unroll
  for (int k = 1; k < 8; ++k) x[k] = cmulcf(x[k], w[k]);
  bfly8_dit(x);
  #pragma unroll
  for (int k = 0; k < 8; ++k) T[i0 + k * q] = x[k];
}

extern "C" __global__ void setup_tables(float2* ws) {
  const int idx = blockIdx.x * 512 + threadIdx.x;
  if (idx < 4096) {
    const long p = ((long)idx * idx) % 16382;      // j^2 mod 2*8191
    const double th = -M_PI * (double)p / 8191.0;
    double s, c; sincos(th, &s, &c);
    ws[WS_C + idx] = make_float2((float)c, (float)s);
  } else if (idx < 8192) {
    const int j = idx - 4096;
    const long p = ((long)j * j) % 16380;          // j^2 mod 2*8190
    const double th = M_PI * (double)p / 8190.0;
    double s, c; sincos(th, &s, &c);
    ws[WS_D + j] = make_float2((float)c, (float)s);
  } else if (idx < 16384) {
    const int j = idx - 8192;
    const double th = -M_PI * (double)j / 4096.0;  // e^{-2pi i j/8192}
    double s, c; sincos(th, &s, &c);
    ws[WS_TW + j] = make_float2((float)c, (float)s);
  }
}

// radix-8 table-twiddle DIF (4 stages) + trailing span-1 r2 — MUST match conv's permutation
template <int NT>
static __device__ void fft8_dif_tab(float2* buf, const float2* __restrict__ tw) {
  const int tid = threadIdx.x;
  for (int s = 0; s < 4; ++s) {
    const int q = 1024 >> (3 * s);
    __syncthreads();
    for (int r = 0; r < 1024 / NT; ++r) {
      const int bid = tid + r * NT;
      const int j   = bid & (q - 1);
      const int i0  = ((bid >> (10 - 3 * s)) << (13 - 3 * s)) + j;
      const int e   = j << (3 * s);
      float2 x[8];
      #pragma unroll
      for (int k = 0; k < 8; ++k) x[k] = buf[i0 + k * q];
      bfly8_dif(x);
      buf[i0] = x[0];
      #pragma unroll
      for (int k = 1; k < 8; ++k) buf[i0 + k * q] = cmulf(x[k], tw[k * e]);
    }
  }
  __syncthreads();
  for (int r = 0; r < 4096 / NT; ++r) {
    const int i0 = (tid + r * NT) << 1;
    const float2 a = buf[i0], b = buf[i0 + 1];
    buf[i0] = cadd(a, b); buf[i0 + 1] = csub(a, b);
  }
  __syncthreads();
}

extern "C" __global__ __launch_bounds__(512, 1) void setup_filters(float2* ws) {
  __shared__ __align__(16) float2 buf[M_];
  const float2* src = ws + (blockIdx.x == 0 ? WS_C : WS_D);
  float2*       dst = ws + (blockIdx.x == 0 ? WS_H1 : WS_H2);
  const float2* tw  = ws + WS_TW;
  for (int i = threadIdx.x; i < M_; i += 512) {
    float2 val = make_float2(0.f, 0.f);
    if (i != 4096) {                       // kernel support |j| <= 4095
      const int jj = (i <= 4095) ? i : (M_ - i);   // chirp is even in j
      const float2 e = src[jj];
      val = make_float2(e.x, -e.y);        // conj(chirp)
    }
    buf[i] = val;
  }
  fft8_dif_tab<512>(buf, tw);
  const float sc = 1.0f / 8192.0f;         // fold IFFT scaling into the filter
  for (int i = threadIdx.x; i < M_; i += 512)
    dst[i] = make_float2(buf[i].x * sc, buf[i].y * sc);
}

// ---------------- projection kernel v3b (unchanged from r11) ----------------
#define PROJ_ISSUE(BUF, IT) { \
  const int s_ = (IT) >> 3, g_ = (IT) & 7; \
  const int l0_ = lbase + (wave << 1) + (g_ << 3); \
  const float4* p_ = (s_ == 0 ? q4p : (s_ == 1 ? k4p : v4p)) + (((size_t)l0_) << 7) + (lane << 2); \
  BUF[0] = p_[0]; \
  BUF[1] = p_[1]; \
  BUF[2] = p_[2]; \
  BUF[3] = p_[3]; }

#define PROJ_REDUCE(BUF, IT) { \
  const int s_ = (IT) >> 3, g_ = (IT) & 7; \
  const int l0_ = lbase + (wave << 1) + (g_ << 3); \
  const float4 w0_ = (s_ == 0 ? wq0 : (s_ == 1 ? wk0 : wv0)); \
  const float4 w1_ = (s_ == 0 ? wq1 : (s_ == 1 ? wk1 : wv1)); \
  const float4 w2_ = (s_ == 0 ? wq2 : (s_ == 1 ? wk2 : wv2)); \
  const float4 w3_ = (s_ == 0 ? wq3 : (s_ == 1 ? wk3 : wv3)); \
  float f_ = BUF[0].x * w0_.x + BUF[0].y * w0_.y + BUF[0].z * w0_.z + BUF[0].w * w0_.w \
           + BUF[1].x * w1_.x + BUF[1].y * w1_.y + BUF[1].z * w1_.z + BUF[1].w * w1_.w \
           + BUF[2].x * w2_.x + BUF[2].y * w2_.y + BUF[2].z * w2_.z + BUF[2].w * w2_.w \
           + BUF[3].x * w3_.x + BUF[3].y * w3_.y + BUF[3].z * w3_.z + BUF[3].w * w3_.w; \
  f_ += __shfl_xor(f_, 1); f_ += __shfl_xor(f_, 2); \
  if (qt == 0) { \
    float* d_ = (s_ == 0 ? q_ws : (s_ == 1 ? k_ws : v_ws)) + (((size_t)(b8 + hh)) << 12) + l0_ + dl; \
    *d_ = f_ + (s_ == 0 ? bq0 : (s_ == 1 ? bk0 : bv0)); } }

extern "C" __global__ __launch_bounds__(256, 4)
void proj_kernel(const float* __restrict__ queries, const float* __restrict__ keys,
                 const float* __restrict__ values,
                 const float* __restrict__ Wq, const float* __restrict__ bq,
                 const float* __restrict__ Wk, const float* __restrict__ bk,
                 const float* __restrict__ Wv, const float* __restrict__ bv,
                 float* __restrict__ q_ws, float* __restrict__ k_ws,
                 float* __restrict__ v_ws)
{
  const int tid  = threadIdx.x;
  const int wave = tid >> 6;           // 0..3
  const int lane = tid & 63;
  const int qt   = lane & 3;           // d-quarter
  const int rr   = lane >> 2;          // 0..15
  const int hh   = rr & 7;             // head
  const int dl   = rr >> 3;            // row offset in chunk (0..1)
  const int blk  = blockIdx.x;         // 2048 blocks
  const int b    = blk >> 6;           // 0..31
  const int b8   = b * 8;
  const int lbase = (blk & 63) << 6;   // 0..4032 step 64

  const float4* q4p = reinterpret_cast<const float4*>(queries) + (size_t)b * 524288;
  const float4* k4p = reinterpret_cast<const float4*>(keys)    + (size_t)b * 524288;
  const float4* v4p = reinterpret_cast<const float4*>(values)  + (size_t)b * 524288;

  const float4* Wq4 = reinterpret_cast<const float4*>(Wq);
  const float4* Wk4 = reinterpret_cast<const float4*>(Wk);
  const float4* Wv4 = reinterpret_cast<const float4*>(Wv);
  const float4 wq0 = Wq4[qt * 4 + 0], wq1 = Wq4[qt * 4 + 1], wq2 = Wq4[qt * 4 + 2], wq3 = Wq4[qt * 4 + 3];
  const float4 wk0 = Wk4[qt * 4 + 0], wk1 = Wk4[qt * 4 + 1], wk2 = Wk4[qt * 4 + 2], wk3 = Wk4[qt * 4 + 3];
  const float4 wv0 = Wv4[qt * 4 + 0], wv1 = Wv4[qt * 4 + 1], wv2 = Wv4[qt * 4 + 2], wv3 = Wv4[qt * 4 + 3];
  const float bq0 = bq[0], bk0 = bk[0], bv0 = bv[0];

  float4 bA[4], bB[4], bC[4];
  PROJ_ISSUE(bA, 0)
  PROJ_ISSUE(bB, 1)
  #pragma unroll
  for (int it = 0; it < 24; ++it) {
    const int nx = it + 2;
    if (nx < 24) {
      if      (nx % 3 == 0) { PROJ_ISSUE(bA, nx) }
      else if (nx % 3 == 1) { PROJ_ISSUE(bB, nx) }
      else                  { PROJ_ISSUE(bC, nx) }
    }
    if      (it % 3 == 0) { PROJ_REDUCE(bA, it) }
    else if (it % 3 == 1) { PROJ_REDUCE(bB, it) }
    else                  { PROJ_REDUCE(bC, it) }
  }
}

// ---------------- main kernel: radix-8 CZT + topk + softmax + gather ----------------
extern "C" __global__ __launch_bounds__(1024, 4)
void autocorr_main(const float2* __restrict__ ws,
                   const float* __restrict__ q_ws, const float* __restrict__ k_ws,
                   const float* __restrict__ v_ws, float* __restrict__ outp)
{
  __shared__ __align__(16) float2 bufA[M_];   // 64 KB (K path, then inverse-CZT)
  __shared__ __align__(16) float2 bufB[M_];   // 64 KB (Q path)
  __shared__ float  v_lds[L_];                // 16 KB
  __shared__ float  cand_v[16 * KK];
  __shared__ int    cand_i[16 * KK];
  __shared__ float  w_sh[KK];
  __shared__ int    i_sh[KK];

  const int tid = threadIdx.x;
  const int bh  = blockIdx.x;

  const float2* c_t = ws + WS_C;
  const float2* d_t = ws + WS_D;
  const float2* H1  = ws + WS_H1;
  const float2* H2  = ws + WS_H2;
  const float* qrow = q_ws + ((size_t)bh << 12);
  const float* krow = k_ws + ((size_t)bh << 12);
  const float* vrow = v_ws + ((size_t)bh << 12);

  // v into LDS (consumed after many barriers)
  {
    const float4 v4 = reinterpret_cast<const float4*>(vrow)[tid];
    reinterpret_cast<float4*>(v_lds)[tid] = v4;
  }

  // ======== conv2 (K in A, Q in B), forward stage 0 FUSED with chirp-premultiply ========
  {
    float2 w[8]; mk_tw(tid, w);      // s=0: e = j = tid
    float2 xA[8], xB[8];
    #pragma unroll
    for (int k = 0; k < 4; ++k) {
      const int m = tid + (k << 10);
      const float2 cc = c_t[m];
      const float kv = krow[m];
      const float qv = qrow[m];
      xA[k] = make_float2(kv * cc.x, kv * cc.y);
      xB[k] = make_float2(qv * cc.x, qv * cc.y);
    }
    #pragma unroll
    for (int k = 4; k < 8; ++k) { xA[k] = make_float2(0.f, 0.f); xB[k] = make_float2(0.f, 0.f); }
    bfly8_dif(xA);
    bfly8_dif(xB);
    bufA[tid] = xA[0];
    bufB[tid] = xB[0];
    #pragma unroll
    for (int k = 1; k < 8; ++k) {
      bufA[tid + (k << 10)] = cmulf(xA[k], w[k]);
      bufB[tid + (k << 10)] = cmulf(xB[k], w[k]);
    }
  }
  __syncthreads();
  r8_fwd_stage(bufA, 1, tid); r8_fwd_stage(bufB, 1, tid);
  __syncthreads();
  r8_fwd_stage(bufA, 2, tid); r8_fwd_stage(bufB, 2, tid);
  __syncthreads();
  megamid((tid >> 9) ? bufB : bufA, H1, tid & 511);
  __syncthreads();
  r8_inv_stage(bufA, 2, tid); r8_inv_stage(bufB, 2, tid);
  __syncthreads();
  r8_inv_stage(bufA, 1, tid); r8_inv_stage(bufB, 1, tid);
  __syncthreads();
  r8_inv_stage(bufA, 0, tid); r8_inv_stage(bufB, 0, tid);
  __syncthreads();

  // ======== conv1 (inverse CZT), forward stage 0 FUSED with F = (cQ)conj(cK), g.d ========
  {
    float2 w[8]; mk_tw(tid, w);
    float2 x[8];
    #pragma unroll
    for (int k = 0; k < 4; ++k) {
      const int m = tid + (k << 10);
      const float2 cc = c_t[m];
      const float2 K = cmulf(cc, bufA[m]);
      const float2 Q = cmulf(cc, bufB[m]);
      const float2 F = cmulcf(Q, K);
      float2 g;
      if (m == 0 || m == 4095) g = make_float2(F.x, 0.f);   // DC/Nyquist: Im dropped
      else                     g = make_float2(2.f * F.x, 2.f * F.y);
      x[k] = cmulf(g, d_t[m]);
    }
    #pragma unroll
    for (int k = 4; k < 8; ++k) x[k] = make_float2(0.f, 0.f);
    bfly8_dif(x);
    bufA[tid] = x[0];
    #pragma unroll
    for (int k = 1; k < 8; ++k) bufA[tid + (k << 10)] = cmulf(x[k], w[k]);
  }
  __syncthreads();
  r8_fwd_stage(bufA, 1, tid);
  __syncthreads();
  r8_fwd_stage(bufA, 2, tid);
  __syncthreads();
  if (tid < 512) megamid(bufA, H2, tid);
  __syncthreads();
  r8_inv_stage(bufA, 2, tid);
  __syncthreads();
  r8_inv_stage(bufA, 1, tid);
  __syncthreads();
  r8_inv_stage(bufA, 0, tid);
  __syncthreads();

  // ---------------- scores + per-wave top-45 ----------------
  const float SCALE = (float)(1.0 / (8190.0 * 4096.0));   // /8190 (irfft) then /4096 (L)
  float svv[4]; int sii[4];
  #pragma unroll
  for (int r = 0; r < 4; ++r) {
    const int t = tid + (r << 10);
    const float2 Z = cmulf(d_t[t], bufA[t]);
    svv[r] = Z.x * SCALE;
    sii[r] = t;
  }
  const int lane = tid & 63, wv = tid >> 6;   // 16 waves
  for (int it = 0; it < KK; ++it) {
    float bvv = -FLT_MAX; int bii = 0x7fffffff;
    #pragma unroll
    for (int c = 0; c < 4; ++c)
      if (svv[c] > bvv || (svv[c] == bvv && sii[c] < bii)) { bvv = svv[c]; bii = sii[c]; }
    #pragma unroll
    for (int off = 1; off < 64; off <<= 1) {
      const float ov = __shfl_xor(bvv, off);
      const int   oi = __shfl_xor(bii, off);
      if (ov > bvv || (ov == bvv && oi < bii)) { bvv = ov; bii = oi; }
    }
    #pragma unroll
    for (int c = 0; c < 4; ++c) if (sii[c] == bii) svv[c] = -FLT_MAX;
    if (lane == 0) { cand_v[wv * KK + it] = bvv; cand_i[wv * KK + it] = bii; }
  }
  __syncthreads();

  // ---------------- merge 16x45 + softmax (wave 0) ----------------
  if (tid < 64) {
    float mv[12]; int mi[12];
    #pragma unroll
    for (int c = 0; c < 12; ++c) {
      const int id = tid + 64 * c;
      if (id < 16 * KK) { mv[c] = cand_v[id]; mi[c] = cand_i[id]; }
      else              { mv[c] = -FLT_MAX;   mi[c] = 0x7fffffff; }
    }
    float m0 = 0.f, sum = 0.f, myv = -FLT_MAX; int myi = 0;
    for (int it = 0; it < KK; ++it) {
      float bvv = -FLT_MAX; int bii = 0x7fffffff;
      #pragma unroll
      for (int c = 0; c < 12; ++c)
        if (mv[c] > bvv || (mv[c] == bvv && mi[c] < bii)) { bvv = mv[c]; bii = mi[c]; }
      #pragma unroll
      for (int off = 1; off < 64; off <<= 1) {
        const float ov = __shfl_xor(bvv, off);
        const int   oi = __shfl_xor(bii, off);
        if (ov > bvv || (ov == bvv && oi < bii)) { bvv = ov; bii = oi; }
      }
      if (it == 0) m0 = bvv;
      sum += expf(bvv - m0);               // identical on all lanes
      if (tid == it) { myv = bvv; myi = bii; }
      #pragma unroll
      for (int c = 0; c < 12; ++c) if (mi[c] == bii) mv[c] = -FLT_MAX;
    }
    if (tid < KK) { w_sh[tid] = expf(myv - m0) / sum; i_sh[tid] = myi; }
  }
  __syncthreads();

  // ---------------- gather: out[t] = sum_j w_j * v[(idx_j + t) & 4095] ------------
  {
    float acc[4] = {0, 0, 0, 0};
    for (int j = 0; j < KK; ++j) {
      const float wj = w_sh[j];
      const int   bse = i_sh[j] + tid;
      #pragma unroll
      for (int r = 0; r < 4; ++r)
        acc[r] = fmaf(wj, v_lds[(bse + (r << 10)) & (L_ - 1)], acc[r]);
    }
    float* op = outp + ((size_t)bh << 12);
    #pragma unroll
    for (int r = 0; r < 4; ++r) op[tid + (r << 10)] = acc[r];
  }
}

extern "C" void kernel_launch(void* const* d_in, const int* in_sizes, int n_in,
                              void* d_out, int out_size, void* d_ws, size_t ws_size,
                              hipStream_t stream) {
  const float* queries = (const float*)d_in[0];
  const float* keys    = (const float*)d_in[1];
  const float* values  = (const float*)d_in[2];
  const float* Wq = (const float*)d_in[3];
  const float* bq = (const float*)d_in[4];
  const float* Wk = (const float*)d_in[5];
  const float* bk = (const float*)d_in[6];
  const float* Wv = (const float*)d_in[7];
  const float* bv = (const float*)d_in[8];
  float2* ws = (float2*)d_ws;
  float* q_ws = (float*)d_ws + 2 * WS_QKV;
  float* k_ws = q_ws + (1 << 20);
  float* v_ws = k_ws + (1 << 20);
  float* out = (float*)d_out;

  hipLaunchKernelGGL(setup_tables,  dim3(32), dim3(512), 0, stream, ws);
  hipLaunchKernelGGL(setup_filters, dim3(2),  dim3(512), 0, stream, ws);
  hipLaunchKernelGGL(proj_kernel,   dim3(2048), dim3(256), 0, stream,
                     queries, keys, values, Wq, bq, Wk, bk, Wv, bv, q_ws, k_ws, v_ws);
  hipLaunchKernelGGL(autocorr_main, dim3(256), dim3(1024), 0, stream,
                     ws, q_ws, k_ws, v_ws, out);
}

// Round 13
// 338.858 us; speedup vs baseline: 1.2197x; 1.2197x over previous
//
#include <hip/hip_runtime.h>
#include <math.h>
#include <float.h>

#define L_   4096
#define M_   8192
#define H_   8
#define D_   64
#define KK   45          // 5 * ceil(ln(4096))

// ws layout in float2 units
#define WS_C   0         // c[4096]  : e^{-i pi j^2 / 8191}
#define WS_D   4096      // d[4096]  : e^{+i pi j^2 / 8190}
#define WS_TW  8192      // tw[8192] : e^{-2 pi i j / 8192} (fp64-accurate; setup_filters only)
#define WS_H1  16384     // H1s[8192]: radix4-DIF(conj-chirp c), pre-scaled 1/8192, digit-reversed
#define WS_H2  24576     // H2s[8192]: same for d
#define WS_QKV 32768     // float2 offset where staged q/k/v planes start
// tables: 256 KB; then q/k/v planes: 3 x 1M floats = 12 MB

__device__ __forceinline__ float2 cadd(float2 a, float2 b) { return make_float2(a.x + b.x, a.y + b.y); }
__device__ __forceinline__ float2 csub(float2 a, float2 b) { return make_float2(a.x - b.x, a.y - b.y); }
__device__ __forceinline__ float2 cmulf(float2 a, float2 b) {
  return make_float2(a.x * b.x - a.y * b.y, a.x * b.y + a.y * b.x);
}
__device__ __forceinline__ float2 cmulcf(float2 a, float2 b) {  // a * conj(b)
  return make_float2(a.x * b.x + a.y * b.y, a.y * b.x - a.x * b.y);
}

// register twiddle: e^{-2 pi i e / 8192}, e in [0, 2048)
__device__ __forceinline__ float2 twf(int e) {
  float s, c;
  __sincosf((float)e * -7.66990394e-4f, &s, &c);   // -2*pi/8192
  return make_float2(c, s);
}

#define R4DIF(BUF) { \
  const float2 a = BUF[i0], b = BUF[i0 + q], c = BUF[i0 + 2 * q], d = BUF[i0 + 3 * q]; \
  const float2 t0 = cadd(a, c), t1 = csub(a, c), t2 = cadd(b, d), t3 = csub(b, d); \
  BUF[i0]         = cadd(t0, t2); \
  BUF[i0 + q]     = cmulf(make_float2(t1.x + t3.y, t1.y - t3.x), w1); \
  BUF[i0 + 2 * q] = cmulf(csub(t0, t2), w2); \
  BUF[i0 + 3 * q] = cmulf(make_float2(t1.x - t3.y, t1.y + t3.x), w3); }

#define R4DIT(BUF) { \
  const float2 z0 = BUF[i0]; \
  const float2 z1 = cmulcf(BUF[i0 + q],     w1); \
  const float2 z2 = cmulcf(BUF[i0 + 2 * q], w2); \
  const float2 z3 = cmulcf(BUF[i0 + 3 * q], w3); \
  const float2 t0 = cadd(z0, z2), t1 = csub(z0, z2), t2 = cadd(z1, z3), u = csub(z1, z3); \
  BUF[i0]         = cadd(t0, t2); \
  BUF[i0 + q]     = make_float2(t1.x - u.y, t1.y + u.x); \
  BUF[i0 + 2 * q] = csub(t0, t2); \
  BUF[i0 + 3 * q] = make_float2(t1.x + u.y, t1.y - u.x); }

// register-array radix-4 butterflies (all indices compile-time at call sites)
__device__ __forceinline__ void bfly4_dif(float2 x[4], float2 w1, float2 w2, float2 w3) {
  const float2 t0 = cadd(x[0], x[2]), t1 = csub(x[0], x[2]);
  const float2 t2 = cadd(x[1], x[3]), t3 = csub(x[1], x[3]);
  x[0] = cadd(t0, t2);
  x[1] = cmulf(make_float2(t1.x + t3.y, t1.y - t3.x), w1);
  x[2] = cmulf(csub(t0, t2), w2);
  x[3] = cmulf(make_float2(t1.x - t3.y, t1.y + t3.x), w3);
}
__device__ __forceinline__ void bfly4_dit(float2 x[4], float2 w1, float2 w2, float2 w3) {
  const float2 z0 = x[0];
  const float2 z1 = cmulcf(x[1], w1);
  const float2 z2 = cmulcf(x[2], w2);
  const float2 z3 = cmulcf(x[3], w3);
  const float2 t0 = cadd(z0, z2), t1 = csub(z0, z2), t2 = cadd(z1, z3), u = csub(z1, z3);
  x[0] = cadd(t0, t2);
  x[1] = make_float2(t1.x - u.y, t1.y + u.x);
  x[2] = csub(t0, t2);
  x[3] = make_float2(t1.x + u.y, t1.y - u.x);
}

// fused r2 + H-pointwise + r2inv on one float2-pair packed in a float4
__device__ __forceinline__ float4 midpair(float4 a, float4 h) {
  float2 u = make_float2(a.x + a.z, a.y + a.w);
  float2 v = make_float2(a.x - a.z, a.y - a.w);
  u = cmulf(u, make_float2(h.x, h.y));
  v = cmulf(v, make_float2(h.z, h.w));
  return make_float4(u.x + v.x, u.y + v.y, u.x - v.x, u.y - v.y);
}

// middle forward stages s=1..5 on two buffers (1024 threads)
static __device__ void fwd_stages2(float2* A, float2* B) {
  const int tid = threadIdx.x;
  #pragma unroll
  for (int s = 1; s < 6; ++s) {
    const int q = 2048 >> (2 * s);
    __syncthreads();
    #pragma unroll
    for (int r = 0; r < 2; ++r) {
      const int bid = tid + (r << 10);
      const int j   = bid & (q - 1);
      const int i0  = ((bid >> (11 - 2 * s)) << (13 - 2 * s)) + j;
      const float2 w1 = twf(j << (2 * s));
      const float2 w2 = cmulf(w1, w1);
      const float2 w3 = cmulf(w2, w1);
      R4DIF(A) R4DIF(B)
    }
  }
}
static __device__ void inv_stages2(float2* A, float2* B) {   // s=5..1
  const int tid = threadIdx.x;
  #pragma unroll
  for (int s = 5; s >= 1; --s) {
    const int q = 2048 >> (2 * s);
    __syncthreads();
    #pragma unroll
    for (int r = 0; r < 2; ++r) {
      const int bid = tid + (r << 10);
      const int j   = bid & (q - 1);
      const int i0  = ((bid >> (11 - 2 * s)) << (13 - 2 * s)) + j;
      const float2 w1 = twf(j << (2 * s));
      const float2 w2 = cmulf(w1, w1);
      const float2 w3 = cmulf(w2, w1);
      R4DIT(A) R4DIT(B)
    }
  }
}
static __device__ void fwd_stages1(float2* A) {
  const int tid = threadIdx.x;
  #pragma unroll
  for (int s = 1; s < 6; ++s) {
    const int q = 2048 >> (2 * s);
    __syncthreads();
    #pragma unroll
    for (int r = 0; r < 2; ++r) {
      const int bid = tid + (r << 10);
      const int j   = bid & (q - 1);
      const int i0  = ((bid >> (11 - 2 * s)) << (13 - 2 * s)) + j;
      const float2 w1 = twf(j << (2 * s));
      const float2 w2 = cmulf(w1, w1);
      const float2 w3 = cmulf(w2, w1);
      R4DIF(A)
    }
  }
}
static __device__ void inv_stages1(float2* A) {
  const int tid = threadIdx.x;
  #pragma unroll
  for (int s = 5; s >= 1; --s) {
    const int q = 2048 >> (2 * s);
    __syncthreads();
    #pragma unroll
    for (int r = 0; r < 2; ++r) {
      const int bid = tid + (r << 10);
      const int j   = bid & (q - 1);
      const int i0  = ((bid >> (11 - 2 * s)) << (13 - 2 * s)) + j;
      const float2 w1 = twf(j << (2 * s));
      const float2 w2 = cmulf(w1, w1);
      const float2 w3 = cmulf(w2, w1);
      R4DIT(A)
    }
  }
}

// ---------------- setup: tables (fp64) + Bluestein filters ----------------
// table-twiddle DIF kept ONLY for setup_filters (must match conv's digit-reversed order)
template <int NT>
static __device__ void fft_dif_tab(float2* buf, const float2* __restrict__ tw) {
  const int tid = threadIdx.x;
  for (int s = 0; s < 6; ++s) {
    const int q = 2048 >> (2 * s);
    __syncthreads();
    for (int r = 0; r < 2048 / NT; ++r) {
      const int bid = tid + r * NT;
      const int j   = bid & (q - 1);
      const int i0  = ((bid >> (11 - 2 * s)) << (13 - 2 * s)) + j;
      const int e   = j << (2 * s);
      const float2 w1 = tw[e], w2 = tw[2 * e], w3 = tw[3 * e];
      R4DIF(buf)
    }
  }
  __syncthreads();
  for (int r = 0; r < 4096 / NT; ++r) {
    const int i0 = (tid + r * NT) << 1;
    const float2 a = buf[i0], b = buf[i0 + 1];
    buf[i0] = cadd(a, b); buf[i0 + 1] = csub(a, b);
  }
  __syncthreads();
}

extern "C" __global__ void setup_tables(float2* ws) {
  const int idx = blockIdx.x * 512 + threadIdx.x;
  if (idx < 4096) {
    const long p = ((long)idx * idx) % 16382;      // j^2 mod 2*8191
    const double th = -M_PI * (double)p / 8191.0;
    double s, c; sincos(th, &s, &c);
    ws[WS_C + idx] = make_float2((float)c, (float)s);
  } else if (idx < 8192) {
    const int j = idx - 4096;
    const long p = ((long)j * j) % 16380;          // j^2 mod 2*8190
    const double th = M_PI * (double)p / 8190.0;
    double s, c; sincos(th, &s, &c);
    ws[WS_D + j] = make_float2((float)c, (float)s);
  } else if (idx < 16384) {
    const int j = idx - 8192;
    const double th = -M_PI * (double)j / 4096.0;  // e^{-2pi i j/8192}
    double s, c; sincos(th, &s, &c);
    ws[WS_TW + j] = make_float2((float)c, (float)s);
  }
}

extern "C" __global__ __launch_bounds__(512, 1) void setup_filters(float2* ws) {
  __shared__ __align__(16) float2 buf[M_];
  const float2* src = ws + (blockIdx.x == 0 ? WS_C : WS_D);
  float2*       dst = ws + (blockIdx.x == 0 ? WS_H1 : WS_H2);
  const float2* tw  = ws + WS_TW;
  for (int i = threadIdx.x; i < M_; i += 512) {
    float2 val = make_float2(0.f, 0.f);
    if (i != 4096) {                       // kernel support |j| <= 4095
      const int jj = (i <= 4095) ? i : (M_ - i);   // chirp is even in j
      const float2 e = src[jj];
      val = make_float2(e.x, -e.y);        // conj(chirp)
    }
    buf[i] = val;
  }
  fft_dif_tab<512>(buf, tw);
  const float sc = 1.0f / 8192.0f;         // fold IFFT scaling into the filter
  for (int i = threadIdx.x; i < M_; i += 512)
    dst[i] = make_float2(buf[i].x * sc, buf[i].y * sc);
}

// ---------------- projection kernel v3b (unchanged from r11) ----------------
#define PROJ_ISSUE(BUF, IT) { \
  const int s_ = (IT) >> 3, g_ = (IT) & 7; \
  const int l0_ = lbase + (wave << 1) + (g_ << 3); \
  const float4* p_ = (s_ == 0 ? q4p : (s_ == 1 ? k4p : v4p)) + (((size_t)l0_) << 7) + (lane << 2); \
  BUF[0] = p_[0]; \
  BUF[1] = p_[1]; \
  BUF[2] = p_[2]; \
  BUF[3] = p_[3]; }

#define PROJ_REDUCE(BUF, IT) { \
  const int s_ = (IT) >> 3, g_ = (IT) & 7; \
  const int l0_ = lbase + (wave << 1) + (g_ << 3); \
  const float4 w0_ = (s_ == 0 ? wq0 : (s_ == 1 ? wk0 : wv0)); \
  const float4 w1_ = (s_ == 0 ? wq1 : (s_ == 1 ? wk1 : wv1)); \
  const float4 w2_ = (s_ == 0 ? wq2 : (s_ == 1 ? wk2 : wv2)); \
  const float4 w3_ = (s_ == 0 ? wq3 : (s_ == 1 ? wk3 : wv3)); \
  float f_ = BUF[0].x * w0_.x + BUF[0].y * w0_.y + BUF[0].z * w0_.z + BUF[0].w * w0_.w \
           + BUF[1].x * w1_.x + BUF[1].y * w1_.y + BUF[1].z * w1_.z + BUF[1].w * w1_.w \
           + BUF[2].x * w2_.x + BUF[2].y * w2_.y + BUF[2].z * w2_.z + BUF[2].w * w2_.w \
           + BUF[3].x * w3_.x + BUF[3].y * w3_.y + BUF[3].z * w3_.z + BUF[3].w * w3_.w; \
  f_ += __shfl_xor(f_, 1); f_ += __shfl_xor(f_, 2); \
  if (qt == 0) { \
    float* d_ = (s_ == 0 ? q_ws : (s_ == 1 ? k_ws : v_ws)) + (((size_t)(b8 + hh)) << 12) + l0_ + dl; \
    *d_ = f_ + (s_ == 0 ? bq0 : (s_ == 1 ? bk0 : bv0)); } }

extern "C" __global__ __launch_bounds__(256, 4)
void proj_kernel(const float* __restrict__ queries, const float* __restrict__ keys,
                 const float* __restrict__ values,
                 const float* __restrict__ Wq, const float* __restrict__ bq,
                 const float* __restrict__ Wk, const float* __restrict__ bk,
                 const float* __restrict__ Wv, const float* __restrict__ bv,
                 float* __restrict__ q_ws, float* __restrict__ k_ws,
                 float* __restrict__ v_ws)
{
  const int tid  = threadIdx.x;
  const int wave = tid >> 6;           // 0..3
  const int lane = tid & 63;
  const int qt   = lane & 3;           // d-quarter
  const int rr   = lane >> 2;          // 0..15
  const int hh   = rr & 7;             // head
  const int dl   = rr >> 3;            // row offset in chunk (0..1)
  const int blk  = blockIdx.x;         // 2048 blocks
  const int b    = blk >> 6;           // 0..31
  const int b8   = b * 8;
  const int lbase = (blk & 63) << 6;   // 0..4032 step 64

  const float4* q4p = reinterpret_cast<const float4*>(queries) + (size_t)b * 524288;
  const float4* k4p = reinterpret_cast<const float4*>(keys)    + (size_t)b * 524288;
  const float4* v4p = reinterpret_cast<const float4*>(values)  + (size_t)b * 524288;

  const float4* Wq4 = reinterpret_cast<const float4*>(Wq);
  const float4* Wk4 = reinterpret_cast<const float4*>(Wk);
  const float4* Wv4 = reinterpret_cast<const float4*>(Wv);
  const float4 wq0 = Wq4[qt * 4 + 0], wq1 = Wq4[qt * 4 + 1], wq2 = Wq4[qt * 4 + 2], wq3 = Wq4[qt * 4 + 3];
  const float4 wk0 = Wk4[qt * 4 + 0], wk1 = Wk4[qt * 4 + 1], wk2 = Wk4[qt * 4 + 2], wk3 = Wk4[qt * 4 + 3];
  const float4 wv0 = Wv4[qt * 4 + 0], wv1 = Wv4[qt * 4 + 1], wv2 = Wv4[qt * 4 + 2], wv3 = Wv4[qt * 4 + 3];
  const float bq0 = bq[0], bk0 = bk[0], bv0 = bv[0];

  float4 bA[4], bB[4], bC[4];
  PROJ_ISSUE(bA, 0)
  PROJ_ISSUE(bB, 1)
  #pragma unroll
  for (int it = 0; it < 24; ++it) {
    const int nx = it + 2;
    if (nx < 24) {
      if      (nx % 3 == 0) { PROJ_ISSUE(bA, nx) }
      else if (nx % 3 == 1) { PROJ_ISSUE(bB, nx) }
      else                  { PROJ_ISSUE(bC, nx) }
    }
    if      (it % 3 == 0) { PROJ_REDUCE(bA, it) }
    else if (it % 3 == 1) { PROJ_REDUCE(bB, it) }
    else                  { PROJ_REDUCE(bC, it) }
  }
}

// ---------------- main kernel: radix-4 CZT with register-fused stage-0 passes ----------
extern "C" __global__ __launch_bounds__(1024, 1)
void autocorr_main(const float2* __restrict__ ws,
                   const float* __restrict__ q_ws, const float* __restrict__ k_ws,
                   const float* __restrict__ v_ws, float* __restrict__ outp)
{
  __shared__ __align__(16) float2 bufA[M_];   // 64 KB (K path, then inverse-CZT)
  __shared__ __align__(16) float2 bufB[M_];   // 64 KB (Q path)
  __shared__ float  v_lds[L_];                // 16 KB
  __shared__ float  cand_v[16 * KK];
  __shared__ int    cand_i[16 * KK];
  __shared__ float  w_sh[KK];
  __shared__ int    i_sh[KK];

  const int tid = threadIdx.x;
  const int bh  = blockIdx.x;

  const float2* c_t = ws + WS_C;
  const float2* d_t = ws + WS_D;
  const float2* H1  = ws + WS_H1;
  const float2* H2  = ws + WS_H2;
  const float* qrow = q_ws + ((size_t)bh << 12);
  const float* krow = k_ws + ((size_t)bh << 12);
  const float* vrow = v_ws + ((size_t)bh << 12);

  // v into LDS (consumed only after many barriers)
  {
    const float4 v4 = reinterpret_cast<const float4*>(vrow)[tid];
    reinterpret_cast<float4*>(v_lds)[tid] = v4;
  }

  // ======== ENTRY FUSION: chirp-premultiply + conv2 forward s=0 (q=2048), registers ======
  #pragma unroll
  for (int r = 0; r < 2; ++r) {
    const int bid = tid + (r << 10);                 // j = i0 = bid (< 2048)
    const float2 w1 = twf(bid);
    const float2 w2 = cmulf(w1, w1);
    const float2 w3 = cmulf(w2, w1);
    const float2 cc0 = c_t[bid], cc1 = c_t[bid + 2048];
    const float k0 = krow[bid], k1 = krow[bid + 2048];
    const float q0 = qrow[bid], q1 = qrow[bid + 2048];
    float2 xa[4] = { make_float2(k0 * cc0.x, k0 * cc0.y),
                     make_float2(k1 * cc1.x, k1 * cc1.y),
                     make_float2(0.f, 0.f), make_float2(0.f, 0.f) };
    float2 xb[4] = { make_float2(q0 * cc0.x, q0 * cc0.y),
                     make_float2(q1 * cc1.x, q1 * cc1.y),
                     make_float2(0.f, 0.f), make_float2(0.f, 0.f) };
    bfly4_dif(xa, w1, w2, w3);
    bfly4_dif(xb, w1, w2, w3);
    #pragma unroll
    for (int k = 0; k < 4; ++k) {
      bufA[bid + k * 2048] = xa[k];
      bufB[bid + k * 2048] = xb[k];
    }
  }

  // conv2 middle: fwd s=1..5, midpair(H1), inv s=5..1
  fwd_stages2(bufA, bufB);
  __syncthreads();
  #pragma unroll
  for (int r = 0; r < 4; ++r) {
    const int p = tid + (r << 10);
    const float4 h = reinterpret_cast<const float4*>(H1)[p];
    reinterpret_cast<float4*>(bufA)[p] = midpair(reinterpret_cast<float4*>(bufA)[p], h);
    reinterpret_cast<float4*>(bufB)[p] = midpair(reinterpret_cast<float4*>(bufB)[p], h);
  }
  inv_stages2(bufA, bufB);
  __syncthreads();

  // ======== MIDDLE FUSION: conv2 inv s=0 + F-build + g.d + conv1 fwd s=0, registers =====
  // Thread-local index set {tid + 1024r + 2048k}: reads (A,B) then writes (A) same set.
  {
    float2 gd[2][2];
    #pragma unroll
    for (int r = 0; r < 2; ++r) {
      const int bid = tid + (r << 10);
      const float2 w1 = twf(bid);
      const float2 w2 = cmulf(w1, w1);
      const float2 w3 = cmulf(w2, w1);
      float2 xa[4], xb[4];
      #pragma unroll
      for (int k = 0; k < 4; ++k) { xa[k] = bufA[bid + k * 2048]; xb[k] = bufB[bid + k * 2048]; }
      bfly4_dit(xa, w1, w2, w3);
      bfly4_dit(xb, w1, w2, w3);
      #pragma unroll
      for (int k = 0; k < 2; ++k) {                  // k>=2 are pad outputs: discarded
        const int m = bid + k * 2048;
        const float2 cc = c_t[m];
        const float2 K = cmulf(cc, xa[k]);
        const float2 Q = cmulf(cc, xb[k]);
        const float2 F = cmulcf(Q, K);
        float2 g;
        if (m == 0 || m == 4095) g = make_float2(F.x, 0.f);   // DC/Nyquist: Im dropped
        else                     g = make_float2(2.f * F.x, 2.f * F.y);
        gd[r][k] = cmulf(g, d_t[m]);
      }
    }
    #pragma unroll
    for (int r = 0; r < 2; ++r) {
      const int bid = tid + (r << 10);
      const float2 w1 = twf(bid);
      const float2 w2 = cmulf(w1, w1);
      const float2 w3 = cmulf(w2, w1);
      float2 x[4] = { gd[r][0], gd[r][1], make_float2(0.f, 0.f), make_float2(0.f, 0.f) };
      bfly4_dif(x, w1, w2, w3);
      #pragma unroll
      for (int k = 0; k < 4; ++k) bufA[bid + k * 2048] = x[k];
    }
  }

  // conv1 middle: fwd s=1..5, midpair(H2), inv s=5..1
  fwd_stages1(bufA);
  __syncthreads();
  #pragma unroll
  for (int r = 0; r < 4; ++r) {
    const int p = tid + (r << 10);
    const float4 h = reinterpret_cast<const float4*>(H2)[p];
    reinterpret_cast<float4*>(bufA)[p] = midpair(reinterpret_cast<float4*>(bufA)[p], h);
  }
  inv_stages1(bufA);
  __syncthreads();

  // ======== EXIT FUSION: conv1 inv s=0 + score, registers ========
  const float SCALE = (float)(1.0 / (8190.0 * 4096.0));   // /8190 (irfft) then /4096 (L)
  float svv[4]; int sii[4];
  #pragma unroll
  for (int r = 0; r < 2; ++r) {
    const int bid = tid + (r << 10);
    const float2 w1 = twf(bid);
    const float2 w2 = cmulf(w1, w1);
    const float2 w3 = cmulf(w2, w1);
    float2 x[4];
    #pragma unroll
    for (int k = 0; k < 4; ++k) x[k] = bufA[bid + k * 2048];
    bfly4_dit(x, w1, w2, w3);
    #pragma unroll
    for (int k = 0; k < 2; ++k) {                    // k>=2 are pad outputs: discarded
      const int t = bid + k * 2048;
      const float2 Z = cmulf(d_t[t], x[k]);
      svv[2 * r + k] = Z.x * SCALE;
      sii[2 * r + k] = t;
    }
  }

  // ---------------- per-wave top-45 ----------------
  const int lane = tid & 63, wv = tid >> 6;   // 16 waves
  for (int it = 0; it < KK; ++it) {
    float bvv = -FLT_MAX; int bii = 0x7fffffff;
    #pragma unroll
    for (int c = 0; c < 4; ++c)
      if (svv[c] > bvv || (svv[c] == bvv && sii[c] < bii)) { bvv = svv[c]; bii = sii[c]; }
    #pragma unroll
    for (int off = 1; off < 64; off <<= 1) {
      const float ov = __shfl_xor(bvv, off);
      const int   oi = __shfl_xor(bii, off);
      if (ov > bvv || (ov == bvv && oi < bii)) { bvv = ov; bii = oi; }
    }
    #pragma unroll
    for (int c = 0; c < 4; ++c) if (sii[c] == bii) svv[c] = -FLT_MAX;
    if (lane == 0) { cand_v[wv * KK + it] = bvv; cand_i[wv * KK + it] = bii; }
  }
  __syncthreads();

  // ---------------- merge 16x45 + softmax (wave 0) ----------------
  if (tid < 64) {
    float mv[12]; int mi[12];
    #pragma unroll
    for (int c = 0; c < 12; ++c) {
      const int id = tid + 64 * c;
      if (id < 16 * KK) { mv[c] = cand_v[id]; mi[c] = cand_i[id]; }
      else              { mv[c] = -FLT_MAX;   mi[c] = 0x7fffffff; }
    }
    float m0 = 0.f, sum = 0.f, myv = -FLT_MAX; int myi = 0;
    for (int it = 0; it < KK; ++it) {
      float bvv = -FLT_MAX; int bii = 0x7fffffff;
      #pragma unroll
      for (int c = 0; c < 12; ++c)
        if (mv[c] > bvv || (mv[c] == bvv && mi[c] < bii)) { bvv = mv[c]; bii = mi[c]; }
      #pragma unroll
      for (int off = 1; off < 64; off <<= 1) {
        const float ov = __shfl_xor(bvv, off);
        const int   oi = __shfl_xor(bii, off);
        if (ov > bvv || (ov == bvv && oi < bii)) { bvv = ov; bii = oi; }
      }
      if (it == 0) m0 = bvv;
      sum += expf(bvv - m0);               // identical on all lanes
      if (tid == it) { myv = bvv; myi = bii; }
      #pragma unroll
      for (int c = 0; c < 12; ++c) if (mi[c] == bii) mv[c] = -FLT_MAX;
    }
    if (tid < KK) { w_sh[tid] = expf(myv - m0) / sum; i_sh[tid] = myi; }
  }
  __syncthreads();

  // ---------------- gather: out[t] = sum_j w_j * v[(idx_j + t) & 4095] ------------
  {
    float acc[4] = {0, 0, 0, 0};
    for (int j = 0; j < KK; ++j) {
      const float wj = w_sh[j];
      const int   bse = i_sh[j] + tid;
      #pragma unroll
      for (int r = 0; r < 4; ++r)
        acc[r] = fmaf(wj, v_lds[(bse + (r << 10)) & (L_ - 1)], acc[r]);
    }
    float* op = outp + ((size_t)bh << 12);
    #pragma unroll
    for (int r = 0; r < 4; ++r) op[tid + (r << 10)] = acc[r];
  }
}

extern "C" void kernel_launch(void* const* d_in, const int* in_sizes, int n_in,
                              void* d_out, int out_size, void* d_ws, size_t ws_size,
                              hipStream_t stream) {
  const float* queries = (const float*)d_in[0];
  const float* keys    = (const float*)d_in[1];
  const float* values  = (const float*)d_in[2];
  const float* Wq = (const float*)d_in[3];
  const float* bq = (const float*)d_in[4];
  const float* Wk = (const float*)d_in[5];
  const float* bk = (const float*)d_in[6];
  const float* Wv = (const float*)d_in[7];
  const float* bv = (const float*)d_in[8];
  float2* ws = (float2*)d_ws;
  float* q_ws = (float*)d_ws + 2 * WS_QKV;
  float* k_ws = q_ws + (1 << 20);
  float* v_ws = k_ws + (1 << 20);
  float* out = (float*)d_out;

  hipLaunchKernelGGL(setup_tables,  dim3(32), dim3(512), 0, stream, ws);
  hipLaunchKernelGGL(setup_filters, dim3(2),  dim3(512), 0, stream, ws);
  hipLaunchKernelGGL(proj_kernel,   dim3(2048), dim3(256), 0, stream,
                     queries, keys, values, Wq, bq, Wk, bk, Wv, bv, q_ws, k_ws, v_ws);
  hipLaunchKernelGGL(autocorr_main, dim3(256), dim3(1024), 0, stream,
                     ws, q_ws, k_ws, v_ws, out);
}